// Round 1
// baseline (94.699 us; speedup 1.0000x reference)
//
#include <hip/hip_runtime.h>
#include <math.h>
#include <stdint.h>

// Chamfer loss, B=16, N=M=4096, D=3, fp32 in/out — MFMA formulation, R10.
//
// d^2(p,t) = |p|^2 + (|t|^2 - 2 p.t); the bracket via v_mfma_f32_32x32x16_f16:
//   A row (candidate): [tx, ty, tz, h1, h2, 0,0,0]   (k=0..7; hi-lane k=8..15 garbage)
//   B col (query):     [-2px,-2py,-2pz, 1, 1, 0,0,0] (k=0..7; k=8..15 ZERO -> annihilates A garbage)
// h1+h2 = two-f16 split of |t|^2 (fp32-accurate). f16 products are exact in the
// fp32 accumulator; only error is f16 point quantization (~1e-3 absmax, passes).
//
// R10 delta vs R9 (75.9us): loop-body micro-opts are exhausted — the compiler
// already emits v_min3_f32 for the paired min chains (VALU floor ~3.4us/SIMD),
// MFMA floor ~1.7us, and R6-R9 occupancy/prefetch/ILP changes were all neutral.
// Remaining controllable time is DISPATCH STRUCTURE: 3 kernels = 2 dependent
// graph-node gaps + a ~1.5-2us single-block finish kernel. R10 removes the
// finish dispatch: last-block-done pattern (threadfence + atomicAdd counter in
// ws, zeroed by prep each iter so re-poison is safe; no dispatch-order
// assumption). Last block reduces the 1024 block sums in the SAME order as the
// old finish kernel -> bit-identical result.
//
// Fixed cost context: harness re-poisons ~256 MB ws each timed iter = ~41.5 us
// of fillBuffer at HBM roofline inside dur_us, + ~10 us graph/launch overhead.
// Untouchable floor ~55 us.

#define BATCH   16
#define NPTS    4096
#define THREADS 256                            // 4 waves/block
#define NITEMS  (2 * BATCH * NPTS)             // 131072
#define MAIN_BLOCKS (2 * BATCH * (NPTS / 128)) // 1024: 128 queries per block

typedef __attribute__((ext_vector_type(8)))  _Float16 half8;
typedef __attribute__((ext_vector_type(16))) float    floatx16;

union Pack16 { float4 f4; _Float16 h[8]; half8 h8; };

__global__ __launch_bounds__(256) void chamfer_prep(
    const float* __restrict__ pred, const float* __restrict__ target,
    float4* __restrict__ packP, float4* __restrict__ packT,
    unsigned int* __restrict__ ctr)
{
    int g = blockIdx.x * 256 + threadIdx.x;       // 0..131071
    if (g == 0) *ctr = 0u;                        // reset last-block counter (ws re-poisoned each iter)
    int arr = g >> 16;                            // 0=pred, 1=target
    int pt  = g & 65535;                          // b*NPTS + n
    const float* src = arr ? target : pred;
    float x = src[pt * 3 + 0];
    float y = src[pt * 3 + 1];
    float z = src[pt * 3 + 2];
    _Float16 hx = (_Float16)x, hy = (_Float16)y, hz = (_Float16)z;
    float xf = (float)hx, yf = (float)hy, zf = (float)hz;
    float t = xf * xf + yf * yf + zf * zf;        // |q|^2 of the QUANTIZED point
    _Float16 h1 = (_Float16)t;
    _Float16 h2 = (_Float16)(t - (float)h1);
    Pack16 p;
    p.h[0] = hx; p.h[1] = hy; p.h[2] = hz; p.h[3] = h1; p.h[4] = h2;
    p.h[5] = (_Float16)0.0f; p.h[6] = (_Float16)0.0f; p.h[7] = (_Float16)0.0f;
    (arr ? packT : packP)[pt] = p.f4;
}

__device__ inline half8 make_bfrag(const Pack16& praw, bool lo) {
    half8 f;
#pragma unroll
    for (int i = 0; i < 8; ++i) f[i] = (_Float16)0.0f;
    if (lo) {
        f[0] = (_Float16)(praw.h[0] * (_Float16)-2.0f);  // exact x2 scale
        f[1] = (_Float16)(praw.h[1] * (_Float16)-2.0f);
        f[2] = (_Float16)(praw.h[2] * (_Float16)-2.0f);
        f[3] = (_Float16)1.0f;
        f[4] = (_Float16)1.0f;
    }
    return f;
}

__global__ __launch_bounds__(THREADS, 4) void chamfer_main(
    const float4* __restrict__ packP, const float4* __restrict__ packT,
    float* __restrict__ blocksum, unsigned int* __restrict__ ctr,
    float* __restrict__ out)
{
    __shared__ float pmin[4][64];   // per-wave mins for its 64 queries
    __shared__ float wsum[2];
    __shared__ float redsum[4];
    __shared__ int   lastflag;

    int tid  = threadIdx.x;
    int lane = tid & 63;
    int wave = tid >> 6;            // 0..3
    int qhalf = wave & 1;           // query half (64 queries)
    int chalf = wave >> 1;          // candidate half (2048 candidates)
    int l31  = lane & 31;
    bool lo  = lane < 32;

    int id = blockIdx.x;
    int ng = id & 31; id >>= 5;     // query group (128 queries)
    int b  = id & 15; id >>= 4;
    int dir = id;                   // 0: queries=pred, candidates=target

    const float4* qpack = dir ? packT : packP;
    const float4* cpack = dir ? packP : packT;

    // Two B fragments per wave: queries [qbase, qbase+32) and [qbase+32, qbase+64).
    size_t qbase = (size_t)b * NPTS + ng * 128 + qhalf * 64;
    Pack16 prA, prB;
    prA.f4 = qpack[qbase + l31];
    prB.f4 = qpack[qbase + 32 + l31];
    half8 bfragA = make_bfrag(prA, lo);
    half8 bfragB = make_bfrag(prB, lo);

    const float4* cb = cpack + (size_t)b * NPTS + chalf * 2048;

    floatx16 zero, mnA, mnB;
#pragma unroll
    for (int r = 0; r < 16; ++r) { zero[r] = 0.0f; mnA[r] = 1e30f; mnB[r] = 1e30f; }

    // 32 tiles x 64 candidates. Each load-pair feeds TWO independent MFMA/min
    // chains (bfragA vs bfragB) -> MFMA result latency on one chain overlaps
    // VALU issue on the other. NOTE: keep this order — the d0->d2 min pairs
    // fuse to v_min3_f32, and keeping only 2 d-tiles live stays under the
    // 128-VGPR cap from launch_bounds(256,4).
#pragma unroll 2
    for (int t = 0; t < 32; ++t) {
        Pack16 a0, a1;
        a0.f4 = cb[t * 64 + l31];
        a1.f4 = cb[t * 64 + 32 + l31];
        floatx16 d0 = __builtin_amdgcn_mfma_f32_32x32x16_f16(a0.h8, bfragA, zero, 0, 0, 0);
        floatx16 d1 = __builtin_amdgcn_mfma_f32_32x32x16_f16(a0.h8, bfragB, zero, 0, 0, 0);
#pragma unroll
        for (int r = 0; r < 16; ++r) mnA[r] = fminf(d0[r], mnA[r]);
#pragma unroll
        for (int r = 0; r < 16; ++r) mnB[r] = fminf(d1[r], mnB[r]);
        floatx16 d2 = __builtin_amdgcn_mfma_f32_32x32x16_f16(a1.h8, bfragA, zero, 0, 0, 0);
        floatx16 d3 = __builtin_amdgcn_mfma_f32_32x32x16_f16(a1.h8, bfragB, zero, 0, 0, 0);
#pragma unroll
        for (int r = 0; r < 16; ++r) mnA[r] = fminf(d2[r], mnA[r]);
#pragma unroll
        for (int r = 0; r < 16; ++r) mnB[r] = fminf(d3[r], mnB[r]);
    }

    // Per-lane 16-reg min trees, fold row-halves across lane^32, publish both
    // query sets (cols l31 / l31+32 of pmin row).
    float mA = fminf(fminf(fminf(mnA[0], mnA[1]),   fminf(mnA[2], mnA[3])),
                     fminf(fminf(mnA[4], mnA[5]),   fminf(mnA[6], mnA[7])));
    mA = fminf(mA, fminf(fminf(fminf(mnA[8], mnA[9]),   fminf(mnA[10], mnA[11])),
                         fminf(fminf(mnA[12], mnA[13]), fminf(mnA[14], mnA[15]))));
    float mB = fminf(fminf(fminf(mnB[0], mnB[1]),   fminf(mnB[2], mnB[3])),
                     fminf(fminf(mnB[4], mnB[5]),   fminf(mnB[6], mnB[7])));
    mB = fminf(mB, fminf(fminf(fminf(mnB[8], mnB[9]),   fminf(mnB[10], mnB[11])),
                         fminf(fminf(mnB[12], mnB[13]), fminf(mnB[14], mnB[15]))));
    mA = fminf(mA, __shfl_xor(mA, 32));
    mB = fminf(mB, __shfl_xor(mB, 32));
    if (lo) {
        pmin[wave][l31]      = mA;
        pmin[wave][l31 + 32] = mB;
    }
    __syncthreads();

    // Waves 0-1: all 64 lanes finish one query each (query = qg*128 + wave*64 + lane):
    // merge candidate halves, add |p|^2, sqrt, full-wave sum.
    if (wave < 2) {
        float mm = fminf(pmin[wave][lane], pmin[wave + 2][lane]);
        Pack16 pr;
        pr.f4 = qpack[(size_t)b * NPTS + ng * 128 + wave * 64 + lane];
        float psq = (float)pr.h[3] + (float)pr.h[4];
        float dist = sqrtf(fmaxf(mm + psq, 0.0f));
#pragma unroll
        for (int off = 1; off <= 32; off <<= 1)
            dist += __shfl_xor(dist, off);
        if (lane == 0) wsum[wave] = dist;
    }
    __syncthreads();

    if (tid == 0) {
        blocksum[blockIdx.x] = wsum[0] + wsum[1];
        __threadfence();                               // release: blocksum visible device-wide
        unsigned int old = atomicAdd(ctr, 1u);         // device-scope by default
        lastflag = (old == (unsigned int)(MAIN_BLOCKS - 1));
    }
    __syncthreads();

    // Last arriving block performs the final reduction (replaces chamfer_finish).
    // Summation order is identical to the old finish kernel -> bit-exact result.
    if (lastflag) {
        __threadfence();                               // acquire: invalidate stale cached blocksum
        float4 v = ((const float4*)blocksum)[tid];     // 1024 block sums = 256 thr x float4
        float s = (v.x + v.y) + (v.z + v.w);
#pragma unroll
        for (int off = 1; off <= 32; off <<= 1)
            s += __shfl_xor(s, off);
        if (lane == 0) redsum[wave] = s;
        __syncthreads();
        if (tid == 0)
            out[0] = (redsum[0] + redsum[1] + redsum[2] + redsum[3]) * (1.0f / (float)NITEMS);
    }
}

extern "C" void kernel_launch(void* const* d_in, const int* in_sizes, int n_in,
                              void* d_out, int out_size, void* d_ws, size_t ws_size,
                              hipStream_t stream) {
    const float* pred   = (const float*)d_in[0];
    const float* target = (const float*)d_in[1];
    float* out = (float*)d_out;

    float4* packP = (float4*)d_ws;                              // 1 MB
    float4* packT = packP + (size_t)BATCH * NPTS;               // 1 MB
    float*  blocksum = (float*)(packT + (size_t)BATCH * NPTS);  // 4 KB
    unsigned int* ctr = (unsigned int*)(blocksum + MAIN_BLOCKS);

    chamfer_prep<<<NITEMS / 256, 256, 0, stream>>>(pred, target, packP, packT, ctr);
    chamfer_main<<<MAIN_BLOCKS, THREADS, 0, stream>>>(packP, packT, blocksum, ctr, out);
}

// Round 2
// 83.128 us; speedup vs baseline: 1.1392x; 1.1392x over previous
//
#include <hip/hip_runtime.h>
#include <math.h>
#include <stdint.h>

// Chamfer loss, B=16, N=M=4096, D=3, fp32 in/out — MFMA formulation, R11.
//
// d^2(p,t) = |p|^2 + (|t|^2 - 2 p.t); the bracket via v_mfma_f32_32x32x16_f16:
//   A row (candidate): [tx, ty, tz, h1, h2, 0,0,0]   (k=0..7; hi-lane k=8..15 garbage)
//   B col (query):     [-2px,-2py,-2pz, 1, 1, 0,0,0] (k=0..7; k=8..15 ZERO -> annihilates A garbage)
// h1+h2 = two-f16 split of |t|^2 (fp32-accurate). f16 products are exact in the
// fp32 accumulator; only error is f16 point quantization (~1e-3 absmax, passes).
//
// R10 POST-MORTEM (94.7us, regression): last-block pattern's per-block
// __threadfence() compiles to buffer_wbl2 sc1 = FULL L2 WRITEBACK (per-XCD L2s
// non-coherent). 1024 blocks x L2 flush serialized ~ +27us inside chamfer_main
// (42.4us, MfmaUtil 14.8, VALUBusy 19, HBM ~0 => pure stall). LESSON: on gfx950
// cross-block communication must use scoped atomic RMWs only (sc0 sc1, straight
// to coherent point, no flush) — NEVER a device fence per block.
//
// R11: keep 2 dispatches, drop blocksum/ctr/last-block entirely. prep zeroes
// out[0] (kernel-end implicit release makes it coherent); each main block does
// ONE atomicAdd(out, partial/NITEMS) — canonical one-atomic-per-block, ~1024
// same-address f32 atomics pipelined at the coherent point, hidden under block
// tail stagger. Order nondeterminism adds <=1e-5 error, well under tolerance.
//
// Fixed cost context: harness re-poisons ~256 MB ws each timed iter = ~41.5 us
// of fillBuffer at HBM roofline inside dur_us, + ~10 us graph/launch overhead.
// Untouchable floor ~55 us.

#define BATCH   16
#define NPTS    4096
#define THREADS 256                            // 4 waves/block
#define NITEMS  (2 * BATCH * NPTS)             // 131072
#define MAIN_BLOCKS (2 * BATCH * (NPTS / 128)) // 1024: 128 queries per block

typedef __attribute__((ext_vector_type(8)))  _Float16 half8;
typedef __attribute__((ext_vector_type(16))) float    floatx16;

union Pack16 { float4 f4; _Float16 h[8]; half8 h8; };

__global__ __launch_bounds__(256) void chamfer_prep(
    const float* __restrict__ pred, const float* __restrict__ target,
    float4* __restrict__ packP, float4* __restrict__ packT,
    float* __restrict__ out)
{
    int g = blockIdx.x * 256 + threadIdx.x;       // 0..131071
    if (g == 0) out[0] = 0.0f;                    // zero accumulator (d_out re-poisoned each iter);
                                                  // kernel-end release makes this coherent before main
    int arr = g >> 16;                            // 0=pred, 1=target
    int pt  = g & 65535;                          // b*NPTS + n
    const float* src = arr ? target : pred;
    float x = src[pt * 3 + 0];
    float y = src[pt * 3 + 1];
    float z = src[pt * 3 + 2];
    _Float16 hx = (_Float16)x, hy = (_Float16)y, hz = (_Float16)z;
    float xf = (float)hx, yf = (float)hy, zf = (float)hz;
    float t = xf * xf + yf * yf + zf * zf;        // |q|^2 of the QUANTIZED point
    _Float16 h1 = (_Float16)t;
    _Float16 h2 = (_Float16)(t - (float)h1);
    Pack16 p;
    p.h[0] = hx; p.h[1] = hy; p.h[2] = hz; p.h[3] = h1; p.h[4] = h2;
    p.h[5] = (_Float16)0.0f; p.h[6] = (_Float16)0.0f; p.h[7] = (_Float16)0.0f;
    (arr ? packT : packP)[pt] = p.f4;
}

__device__ inline half8 make_bfrag(const Pack16& praw, bool lo) {
    half8 f;
#pragma unroll
    for (int i = 0; i < 8; ++i) f[i] = (_Float16)0.0f;
    if (lo) {
        f[0] = (_Float16)(praw.h[0] * (_Float16)-2.0f);  // exact x2 scale
        f[1] = (_Float16)(praw.h[1] * (_Float16)-2.0f);
        f[2] = (_Float16)(praw.h[2] * (_Float16)-2.0f);
        f[3] = (_Float16)1.0f;
        f[4] = (_Float16)1.0f;
    }
    return f;
}

__global__ __launch_bounds__(THREADS, 4) void chamfer_main(
    const float4* __restrict__ packP, const float4* __restrict__ packT,
    float* __restrict__ out)
{
    __shared__ float pmin[4][64];   // per-wave mins for its 64 queries
    __shared__ float wsum[2];

    int tid  = threadIdx.x;
    int lane = tid & 63;
    int wave = tid >> 6;            // 0..3
    int qhalf = wave & 1;           // query half (64 queries)
    int chalf = wave >> 1;          // candidate half (2048 candidates)
    int l31  = lane & 31;
    bool lo  = lane < 32;

    int id = blockIdx.x;
    int ng = id & 31; id >>= 5;     // query group (128 queries)
    int b  = id & 15; id >>= 4;
    int dir = id;                   // 0: queries=pred, candidates=target

    const float4* qpack = dir ? packT : packP;
    const float4* cpack = dir ? packP : packT;

    // Two B fragments per wave: queries [qbase, qbase+32) and [qbase+32, qbase+64).
    size_t qbase = (size_t)b * NPTS + ng * 128 + qhalf * 64;
    Pack16 prA, prB;
    prA.f4 = qpack[qbase + l31];
    prB.f4 = qpack[qbase + 32 + l31];
    half8 bfragA = make_bfrag(prA, lo);
    half8 bfragB = make_bfrag(prB, lo);

    const float4* cb = cpack + (size_t)b * NPTS + chalf * 2048;

    floatx16 zero, mnA, mnB;
#pragma unroll
    for (int r = 0; r < 16; ++r) { zero[r] = 0.0f; mnA[r] = 1e30f; mnB[r] = 1e30f; }

    // 32 tiles x 64 candidates. Each load-pair feeds TWO independent MFMA/min
    // chains (bfragA vs bfragB) -> MFMA result latency on one chain overlaps
    // VALU issue on the other. NOTE: keep this order — the d0->d2 min pairs
    // fuse to v_min3_f32, and keeping only 2 d-tiles live stays under the
    // 128-VGPR cap from launch_bounds(256,4).
#pragma unroll 2
    for (int t = 0; t < 32; ++t) {
        Pack16 a0, a1;
        a0.f4 = cb[t * 64 + l31];
        a1.f4 = cb[t * 64 + 32 + l31];
        floatx16 d0 = __builtin_amdgcn_mfma_f32_32x32x16_f16(a0.h8, bfragA, zero, 0, 0, 0);
        floatx16 d1 = __builtin_amdgcn_mfma_f32_32x32x16_f16(a0.h8, bfragB, zero, 0, 0, 0);
#pragma unroll
        for (int r = 0; r < 16; ++r) mnA[r] = fminf(d0[r], mnA[r]);
#pragma unroll
        for (int r = 0; r < 16; ++r) mnB[r] = fminf(d1[r], mnB[r]);
        floatx16 d2 = __builtin_amdgcn_mfma_f32_32x32x16_f16(a1.h8, bfragA, zero, 0, 0, 0);
        floatx16 d3 = __builtin_amdgcn_mfma_f32_32x32x16_f16(a1.h8, bfragB, zero, 0, 0, 0);
#pragma unroll
        for (int r = 0; r < 16; ++r) mnA[r] = fminf(d2[r], mnA[r]);
#pragma unroll
        for (int r = 0; r < 16; ++r) mnB[r] = fminf(d3[r], mnB[r]);
    }

    // Per-lane 16-reg min trees, fold row-halves across lane^32, publish both
    // query sets (cols l31 / l31+32 of pmin row).
    float mA = fminf(fminf(fminf(mnA[0], mnA[1]),   fminf(mnA[2], mnA[3])),
                     fminf(fminf(mnA[4], mnA[5]),   fminf(mnA[6], mnA[7])));
    mA = fminf(mA, fminf(fminf(fminf(mnA[8], mnA[9]),   fminf(mnA[10], mnA[11])),
                         fminf(fminf(mnA[12], mnA[13]), fminf(mnA[14], mnA[15]))));
    float mB = fminf(fminf(fminf(mnB[0], mnB[1]),   fminf(mnB[2], mnB[3])),
                     fminf(fminf(mnB[4], mnB[5]),   fminf(mnB[6], mnB[7])));
    mB = fminf(mB, fminf(fminf(fminf(mnB[8], mnB[9]),   fminf(mnB[10], mnB[11])),
                         fminf(fminf(mnB[12], mnB[13]), fminf(mnB[14], mnB[15]))));
    mA = fminf(mA, __shfl_xor(mA, 32));
    mB = fminf(mB, __shfl_xor(mB, 32));
    if (lo) {
        pmin[wave][l31]      = mA;
        pmin[wave][l31 + 32] = mB;
    }
    __syncthreads();

    // Waves 0-1: all 64 lanes finish one query each (query = qg*128 + wave*64 + lane):
    // merge candidate halves, add |p|^2, sqrt, full-wave sum.
    if (wave < 2) {
        float mm = fminf(pmin[wave][lane], pmin[wave + 2][lane]);
        Pack16 pr;
        pr.f4 = qpack[(size_t)b * NPTS + ng * 128 + wave * 64 + lane];
        float psq = (float)pr.h[3] + (float)pr.h[4];
        float dist = sqrtf(fmaxf(mm + psq, 0.0f));
#pragma unroll
        for (int off = 1; off <= 32; off <<= 1)
            dist += __shfl_xor(dist, off);
        if (lane == 0) wsum[wave] = dist;
    }
    __syncthreads();

    // ONE scoped atomic RMW per block (sc0 sc1 -> coherent point, no L2 flush).
    // No fence, no counter, no last-block reduction.
    if (tid == 0)
        atomicAdd(out, (wsum[0] + wsum[1]) * (1.0f / (float)NITEMS));
}

extern "C" void kernel_launch(void* const* d_in, const int* in_sizes, int n_in,
                              void* d_out, int out_size, void* d_ws, size_t ws_size,
                              hipStream_t stream) {
    const float* pred   = (const float*)d_in[0];
    const float* target = (const float*)d_in[1];
    float* out = (float*)d_out;

    float4* packP = (float4*)d_ws;                              // 1 MB
    float4* packT = packP + (size_t)BATCH * NPTS;               // 1 MB

    chamfer_prep<<<NITEMS / 256, 256, 0, stream>>>(pred, target, packP, packT, out);
    chamfer_main<<<MAIN_BLOCKS, THREADS, 0, stream>>>(packP, packT, out);
}

// Round 3
// 79.409 us; speedup vs baseline: 1.1926x; 1.0468x over previous
//
#include <hip/hip_runtime.h>
#include <math.h>
#include <stdint.h>

// Chamfer loss, B=16, N=M=4096, D=3, fp32 in/out — MFMA formulation, R12.
//
// d^2(p,t) = |p|^2 + (|t|^2 - 2 p.t); the bracket via v_mfma_f32_32x32x16_f16:
//   A row (candidate): [tx, ty, tz, h1, h2, 0,0,0]   (k=0..7; hi-lane k=8..15 garbage)
//   B col (query):     [-2px,-2py,-2pz, 1, 1, 0,0,0] (k=0..7; k=8..15 ZERO -> annihilates A garbage)
// h1+h2 = two-f16 split of |t|^2 (fp32-accurate). f16 products are exact in the
// fp32 accumulator; only error is f16 point quantization (~1e-3, passes).
//
// R10 POST-MORTEM (94.7us): per-block __threadfence() = buffer_wbl2 sc1 (full
// L2 writeback, non-coherent per-XCD L2s) -> +27us stall. NEVER fence per block.
// R11 POST-MORTEM (83.1us): one atomicAdd(out) per block is still a BURST —
// 1024 co-resident lockstep blocks finish within ~1us, 1024 same-address
// coherent-point RMWs serialize (~10ns each) into a ~10us end-of-pipe drain
// tail. Plain cached blocksum stores + a 1.5us finish dispatch are CHEAPER.
//
// R12: restore the 3-dispatch skeleton (prep / main / finish, plain stores),
// and attack main's real limiter: TLP. R10 counters showed main active at only
// ~54% VALUBusy, Occupancy ~27% — 1024 blocks x 4 waves = 4096 waves on 8192
// slots, 4 waves/SIMD can't hide L2+MFMA latency on the load->MFMA->min3 chain.
// Now: 2048 blocks x 64 queries, each wave owns ONE 32-query B-fragment and a
// 2048-candidate half; launch_bounds(256,8) -> 8 blocks/CU = 32 waves/CU (full).
// Single min-chain per wave keeps VGPR <= 64 (required for 8 waves/SIMD).
//
// Fixed cost context: harness re-poisons ~256 MB ws each timed iter = ~41.5 us
// of fillBuffer at HBM roofline inside dur_us, + ~10 us graph/launch overhead.
// Untouchable floor ~55 us.

#define BATCH   16
#define NPTS    4096
#define THREADS 256                            // 4 waves/block
#define NITEMS  (2 * BATCH * NPTS)             // 131072
#define MAIN_BLOCKS (2 * BATCH * (NPTS / 64))  // 2048: 64 queries per block

typedef __attribute__((ext_vector_type(8)))  _Float16 half8;
typedef __attribute__((ext_vector_type(16))) float    floatx16;

union Pack16 { float4 f4; _Float16 h[8]; half8 h8; };

__global__ __launch_bounds__(256) void chamfer_prep(
    const float* __restrict__ pred, const float* __restrict__ target,
    float4* __restrict__ packP, float4* __restrict__ packT)
{
    int g = blockIdx.x * 256 + threadIdx.x;       // 0..131071
    int arr = g >> 16;                            // 0=pred, 1=target
    int pt  = g & 65535;                          // b*NPTS + n
    const float* src = arr ? target : pred;
    float x = src[pt * 3 + 0];
    float y = src[pt * 3 + 1];
    float z = src[pt * 3 + 2];
    _Float16 hx = (_Float16)x, hy = (_Float16)y, hz = (_Float16)z;
    float xf = (float)hx, yf = (float)hy, zf = (float)hz;
    float t = xf * xf + yf * yf + zf * zf;        // |q|^2 of the QUANTIZED point
    _Float16 h1 = (_Float16)t;
    _Float16 h2 = (_Float16)(t - (float)h1);
    Pack16 p;
    p.h[0] = hx; p.h[1] = hy; p.h[2] = hz; p.h[3] = h1; p.h[4] = h2;
    p.h[5] = (_Float16)0.0f; p.h[6] = (_Float16)0.0f; p.h[7] = (_Float16)0.0f;
    (arr ? packT : packP)[pt] = p.f4;
}

__device__ inline half8 make_bfrag(const Pack16& praw, bool lo) {
    half8 f;
#pragma unroll
    for (int i = 0; i < 8; ++i) f[i] = (_Float16)0.0f;
    if (lo) {
        f[0] = (_Float16)(praw.h[0] * (_Float16)-2.0f);  // exact x2 scale
        f[1] = (_Float16)(praw.h[1] * (_Float16)-2.0f);
        f[2] = (_Float16)(praw.h[2] * (_Float16)-2.0f);
        f[3] = (_Float16)1.0f;
        f[4] = (_Float16)1.0f;
    }
    return f;
}

__global__ __launch_bounds__(THREADS, 8) void chamfer_main(
    const float4* __restrict__ packP, const float4* __restrict__ packT,
    float* __restrict__ blocksum)
{
    __shared__ float pmin[4][32];   // per-wave mins for its 32 queries

    int tid  = threadIdx.x;
    int lane = tid & 63;
    int wave = tid >> 6;            // 0..3
    int qhalf = wave & 1;           // which 32-query set
    int chalf = wave >> 1;          // candidate half (2048 candidates)
    int l31  = lane & 31;
    bool lo  = lane < 32;

    int id = blockIdx.x;
    int ng = id & 63; id >>= 6;     // query group (64 queries)
    int b  = id & 15; id >>= 4;
    int dir = id;                   // 0: queries=pred, candidates=target

    const float4* qpack = dir ? packT : packP;
    const float4* cpack = dir ? packP : packT;

    // One B fragment per wave: queries [qbase, qbase+32).
    size_t qbase = (size_t)b * NPTS + ng * 64 + qhalf * 32;
    Pack16 prA;
    prA.f4 = qpack[qbase + l31];
    half8 bfrag = make_bfrag(prA, lo);

    const float4* cb = cpack + (size_t)b * NPTS + chalf * 2048;

    floatx16 zero, mn;
#pragma unroll
    for (int r = 0; r < 16; ++r) { zero[r] = 0.0f; mn[r] = 1e30f; }

    // 32 tiles x 64 candidates; two MFMAs per tile off one bfrag. With 8
    // waves/SIMD, TLP (not per-wave ILP) hides load + MFMA latency; the
    // single min-chain keeps VGPR <= 64 so all 8 waves fit.
#pragma unroll 2
    for (int t = 0; t < 32; ++t) {
        Pack16 a0, a1;
        a0.f4 = cb[t * 64 + l31];
        a1.f4 = cb[t * 64 + 32 + l31];
        floatx16 d0 = __builtin_amdgcn_mfma_f32_32x32x16_f16(a0.h8, bfrag, zero, 0, 0, 0);
        floatx16 d1 = __builtin_amdgcn_mfma_f32_32x32x16_f16(a1.h8, bfrag, zero, 0, 0, 0);
#pragma unroll
        for (int r = 0; r < 16; ++r) mn[r] = fminf(d0[r], mn[r]);
#pragma unroll
        for (int r = 0; r < 16; ++r) mn[r] = fminf(d1[r], mn[r]);
    }

    // Per-lane 16-reg min tree, fold row-halves across lane^32, publish.
    float m = fminf(fminf(fminf(mn[0], mn[1]),   fminf(mn[2], mn[3])),
                    fminf(fminf(mn[4], mn[5]),   fminf(mn[6], mn[7])));
    m = fminf(m, fminf(fminf(fminf(mn[8], mn[9]),   fminf(mn[10], mn[11])),
                       fminf(fminf(mn[12], mn[13]), fminf(mn[14], mn[15]))));
    m = fminf(m, __shfl_xor(m, 32));
    if (lo) pmin[wave][l31] = m;
    __syncthreads();

    // Wave 0: 64 lanes finish one query each (query = ng*64 + lane):
    // merge candidate halves, add |p|^2, sqrt, full-wave sum, one plain store.
    if (wave == 0) {
        int qh = lane >> 5;
        float mm = fminf(pmin[qh][l31], pmin[qh + 2][l31]);
        Pack16 pr;
        pr.f4 = qpack[(size_t)b * NPTS + ng * 64 + lane];
        float psq = (float)pr.h[3] + (float)pr.h[4];
        float dist = sqrtf(fmaxf(mm + psq, 0.0f));
#pragma unroll
        for (int off = 1; off <= 32; off <<= 1)
            dist += __shfl_xor(dist, off);
        if (lane == 0) blocksum[blockIdx.x] = dist;
    }
}

__global__ __launch_bounds__(256) void chamfer_finish(
    const float4* __restrict__ bs, float* __restrict__ out)
{
    __shared__ float ws[4];
    int tid = threadIdx.x;
    float4 v0 = bs[tid];                  // 2048 block sums = 256 thr x 2 float4
    float4 v1 = bs[tid + 256];
    float s = ((v0.x + v0.y) + (v0.z + v0.w)) + ((v1.x + v1.y) + (v1.z + v1.w));
#pragma unroll
    for (int off = 1; off <= 32; off <<= 1)
        s += __shfl_xor(s, off);
    int lane = tid & 63, wave = tid >> 6;
    if (lane == 0) ws[wave] = s;
    __syncthreads();
    if (tid == 0) out[0] = (ws[0] + ws[1] + ws[2] + ws[3]) * (1.0f / (float)NITEMS);
}

extern "C" void kernel_launch(void* const* d_in, const int* in_sizes, int n_in,
                              void* d_out, int out_size, void* d_ws, size_t ws_size,
                              hipStream_t stream) {
    const float* pred   = (const float*)d_in[0];
    const float* target = (const float*)d_in[1];
    float* out = (float*)d_out;

    float4* packP = (float4*)d_ws;                              // 1 MB
    float4* packT = packP + (size_t)BATCH * NPTS;               // 1 MB
    float*  blocksum = (float*)(packT + (size_t)BATCH * NPTS);  // 8 KB

    chamfer_prep<<<NITEMS / 256, 256, 0, stream>>>(pred, target, packP, packT);
    chamfer_main<<<MAIN_BLOCKS, THREADS, 0, stream>>>(packP, packT, blocksum);
    chamfer_finish<<<1, 256, 0, stream>>>((const float4*)blocksum, out);
}

// Round 4
// 76.485 us; speedup vs baseline: 1.2381x; 1.0382x over previous
//
#include <hip/hip_runtime.h>
#include <math.h>
#include <stdint.h>

// Chamfer loss, B=16, N=M=4096, D=3, fp32 in/out — MFMA formulation, R13.
//
// d^2(p,t) = |p|^2 + (|t|^2 - 2 p.t); the bracket via v_mfma_f32_32x32x16_f16:
//   A row (candidate): [tx, ty, tz, h1, h2, 0,0,0]   (k=0..7; hi-lane k=8..15 garbage)
//   B col (query):     [-2px,-2py,-2pz, 1, 1, 0,0,0] (k=0..7; k=8..15 ZERO -> annihilates A garbage)
// h1+h2 = two-f16 split of |t|^2 (fp32-accurate). Only error is f16 point
// quantization (~1e-3, passes).
//
// HISTORY: R9=76.0 (1024 blk dual-chain, proven best). R10=94.7 (per-block
// __threadfence = L2 writeback, NEVER). R11=83.1 (1024 same-address atomics =
// serialized burst tail, NEVER). R12=79.4 (TLP via 2048 blk + lb(256,8):
// REFUTED — 64-VGPR clamp serialized/spilled; compiler-scheduled occupancy
// tweaks are exhausted).
//
// R13 theory: main (~15us vs ~4-5us issue floor) is LATENCY-bound: ~64 MB of
// candidate re-reads, ~13% L2-miss (FETCH 8.2MB, ~450-900cy) + L2 hits
// (~200cy), but compiler keeps only ~2-4 loads in flight/wave (R8's VGPR=40
// shows it collapses register prefetch). Fix = decouple load from consume
// WITHOUT VGPRs and WITHOUT block barriers: per-wave private 4-slot LDS ring
// filled by __builtin_amdgcn_global_load_lds (1 instr = 64 lanes x 16B = one
// 64-candidate tile), prefetch depth 3, counted s_waitcnt vmcnt(2) (never 0
// in-loop) + sched_barrier(0) at iteration boundaries (rule #18). Slot reuse
// is race-free: the gll for slot s issues after the MFMAs that consumed s
// (lgkmcnt-before-MFMA => ds_reads complete before gll issue). Tail peeled
// vmcnt(2/1/0). Geometry/body = R9 verbatim otherwise.
//
// Fixed cost context: harness re-poisons ~256 MB ws each timed iter = ~41.5 us
// of fillBuffer at HBM roofline inside dur_us, + ~10 us graph/launch overhead.
// Untouchable floor ~55 us.

#define BATCH   16
#define NPTS    4096
#define THREADS 256                            // 4 waves/block
#define NITEMS  (2 * BATCH * NPTS)             // 131072
#define MAIN_BLOCKS (2 * BATCH * (NPTS / 128)) // 1024: 128 queries per block

typedef __attribute__((ext_vector_type(8)))  _Float16 half8;
typedef __attribute__((ext_vector_type(16))) float    floatx16;

union Pack16 { float4 f4; _Float16 h[8]; half8 h8; };

// global->LDS DMA: wave-uniform LDS base, per-lane global addr, 16 B/lane.
#define GLL(gsrc, ldst)                                                        \
    __builtin_amdgcn_global_load_lds(                                          \
        (const __attribute__((address_space(1))) void*)(gsrc),                 \
        (__attribute__((address_space(3))) void*)(ldst), 16, 0, 0)

__global__ __launch_bounds__(256) void chamfer_prep(
    const float* __restrict__ pred, const float* __restrict__ target,
    float4* __restrict__ packP, float4* __restrict__ packT)
{
    int g = blockIdx.x * 256 + threadIdx.x;       // 0..131071
    int arr = g >> 16;                            // 0=pred, 1=target
    int pt  = g & 65535;                          // b*NPTS + n
    const float* src = arr ? target : pred;
    float x = src[pt * 3 + 0];
    float y = src[pt * 3 + 1];
    float z = src[pt * 3 + 2];
    _Float16 hx = (_Float16)x, hy = (_Float16)y, hz = (_Float16)z;
    float xf = (float)hx, yf = (float)hy, zf = (float)hz;
    float t = xf * xf + yf * yf + zf * zf;        // |q|^2 of the QUANTIZED point
    _Float16 h1 = (_Float16)t;
    _Float16 h2 = (_Float16)(t - (float)h1);
    Pack16 p;
    p.h[0] = hx; p.h[1] = hy; p.h[2] = hz; p.h[3] = h1; p.h[4] = h2;
    p.h[5] = (_Float16)0.0f; p.h[6] = (_Float16)0.0f; p.h[7] = (_Float16)0.0f;
    (arr ? packT : packP)[pt] = p.f4;
}

__device__ inline half8 make_bfrag(const Pack16& praw, bool lo) {
    half8 f;
#pragma unroll
    for (int i = 0; i < 8; ++i) f[i] = (_Float16)0.0f;
    if (lo) {
        f[0] = (_Float16)(praw.h[0] * (_Float16)-2.0f);  // exact x2 scale
        f[1] = (_Float16)(praw.h[1] * (_Float16)-2.0f);
        f[2] = (_Float16)(praw.h[2] * (_Float16)-2.0f);
        f[3] = (_Float16)1.0f;
        f[4] = (_Float16)1.0f;
    }
    return f;
}

__global__ __launch_bounds__(THREADS, 4) void chamfer_main(
    const float4* __restrict__ packP, const float4* __restrict__ packT,
    float* __restrict__ blocksum)
{
    __shared__ Pack16 ring[4][4][64];  // [wave][slot][candidate] = 16 KB
    __shared__ float pmin[4][64];      // per-wave mins for its 64 queries
    __shared__ float wsum[2];

    int tid  = threadIdx.x;
    int lane = tid & 63;
    int wave = tid >> 6;            // 0..3
    int qhalf = wave & 1;           // query half (64 queries)
    int chalf = wave >> 1;          // candidate half (2048 candidates)
    int l31  = lane & 31;
    bool lo  = lane < 32;

    int id = blockIdx.x;
    int ng = id & 31; id >>= 5;     // query group (128 queries)
    int b  = id & 15; id >>= 4;
    int dir = id;                   // 0: queries=pred, candidates=target

    const float4* qpack = dir ? packT : packP;
    const float4* cpack = dir ? packP : packT;

    // Two B fragments per wave: queries [qbase, qbase+32) and [qbase+32, qbase+64).
    size_t qbase = (size_t)b * NPTS + ng * 128 + qhalf * 64;
    Pack16 prA, prB;
    prA.f4 = qpack[qbase + l31];
    prB.f4 = qpack[qbase + 32 + l31];
    half8 bfragA = make_bfrag(prA, lo);
    half8 bfragB = make_bfrag(prB, lo);

    const float4* cb = cpack + (size_t)b * NPTS + chalf * 2048;

    floatx16 zero, mnA, mnB;
#pragma unroll
    for (int r = 0; r < 16; ++r) { zero[r] = 0.0f; mnA[r] = 1e30f; mnB[r] = 1e30f; }

    // Prologue: DMA tiles 0..2 into ring slots 0..2 (3 in flight).
    GLL(cb + 0 * 64 + lane, &ring[wave][0][0]);
    GLL(cb + 1 * 64 + lane, &ring[wave][1][0]);
    GLL(cb + 2 * 64 + lane, &ring[wave][2][0]);

    // One tile = 64 candidates. Consume tile t from slot t&3, prefetch tile
    // t+3 into slot (t+3)&3 (= slot consumed at t-1, whose ds_reads are
    // complete: they fed MFMAs that precede this gll in program order).
    // vmcnt(2) = counted wait for tile t only; never drains the pipeline.
#define TILE_BODY(t_)                                                          \
    {                                                                          \
        const Pack16* sl = &ring[wave][(t_) & 3][0];                           \
        Pack16 a0, a1;                                                         \
        a0.f4 = sl[l31].f4;                                                    \
        a1.f4 = sl[32 + l31].f4;                                               \
        floatx16 d0 = __builtin_amdgcn_mfma_f32_32x32x16_f16(a0.h8, bfragA, zero, 0, 0, 0); \
        floatx16 d1 = __builtin_amdgcn_mfma_f32_32x32x16_f16(a0.h8, bfragB, zero, 0, 0, 0); \
        _Pragma("unroll")                                                      \
        for (int r = 0; r < 16; ++r) mnA[r] = fminf(d0[r], mnA[r]);            \
        _Pragma("unroll")                                                      \
        for (int r = 0; r < 16; ++r) mnB[r] = fminf(d1[r], mnB[r]);            \
        floatx16 d2 = __builtin_amdgcn_mfma_f32_32x32x16_f16(a1.h8, bfragA, zero, 0, 0, 0); \
        floatx16 d3 = __builtin_amdgcn_mfma_f32_32x32x16_f16(a1.h8, bfragB, zero, 0, 0, 0); \
        _Pragma("unroll")                                                      \
        for (int r = 0; r < 16; ++r) mnA[r] = fminf(d2[r], mnA[r]);            \
        _Pragma("unroll")                                                      \
        for (int r = 0; r < 16; ++r) mnB[r] = fminf(d3[r], mnB[r]);            \
    }

#pragma unroll 1
    for (int t = 0; t < 29; ++t) {
        asm volatile("s_waitcnt vmcnt(2)" ::: "memory");
        __builtin_amdgcn_sched_barrier(0);
        TILE_BODY(t);
        GLL(cb + (t + 3) * 64 + lane, &ring[wave][(t + 3) & 3][0]);
    }
    // Peeled tail: in-flight after t=28 is {29,30,31}.
    asm volatile("s_waitcnt vmcnt(2)" ::: "memory");
    __builtin_amdgcn_sched_barrier(0);
    TILE_BODY(29);
    asm volatile("s_waitcnt vmcnt(1)" ::: "memory");
    __builtin_amdgcn_sched_barrier(0);
    TILE_BODY(30);
    asm volatile("s_waitcnt vmcnt(0)" ::: "memory");
    __builtin_amdgcn_sched_barrier(0);
    TILE_BODY(31);
#undef TILE_BODY

    // Per-lane 16-reg min trees, fold row-halves across lane^32, publish both
    // query sets (cols l31 / l31+32 of pmin row).
    float mA = fminf(fminf(fminf(mnA[0], mnA[1]),   fminf(mnA[2], mnA[3])),
                     fminf(fminf(mnA[4], mnA[5]),   fminf(mnA[6], mnA[7])));
    mA = fminf(mA, fminf(fminf(fminf(mnA[8], mnA[9]),   fminf(mnA[10], mnA[11])),
                         fminf(fminf(mnA[12], mnA[13]), fminf(mnA[14], mnA[15]))));
    float mB = fminf(fminf(fminf(mnB[0], mnB[1]),   fminf(mnB[2], mnB[3])),
                     fminf(fminf(mnB[4], mnB[5]),   fminf(mnB[6], mnB[7])));
    mB = fminf(mB, fminf(fminf(fminf(mnB[8], mnB[9]),   fminf(mnB[10], mnB[11])),
                         fminf(fminf(mnB[12], mnB[13]), fminf(mnB[14], mnB[15]))));
    mA = fminf(mA, __shfl_xor(mA, 32));
    mB = fminf(mB, __shfl_xor(mB, 32));
    if (lo) {
        pmin[wave][l31]      = mA;
        pmin[wave][l31 + 32] = mB;
    }
    __syncthreads();

    // Waves 0-1: all 64 lanes finish one query each (query = qg*128 + wave*64 + lane):
    // merge candidate halves, add |p|^2, sqrt, full-wave sum.
    if (wave < 2) {
        float mm = fminf(pmin[wave][lane], pmin[wave + 2][lane]);
        Pack16 pr;
        pr.f4 = qpack[(size_t)b * NPTS + ng * 128 + wave * 64 + lane];
        float psq = (float)pr.h[3] + (float)pr.h[4];
        float dist = sqrtf(fmaxf(mm + psq, 0.0f));
#pragma unroll
        for (int off = 1; off <= 32; off <<= 1)
            dist += __shfl_xor(dist, off);
        if (lane == 0) wsum[wave] = dist;
    }
    __syncthreads();

    if (tid == 0)
        blocksum[blockIdx.x] = wsum[0] + wsum[1];
}

__global__ __launch_bounds__(256) void chamfer_finish(
    const float4* __restrict__ bs, float* __restrict__ out)
{
    __shared__ float ws[4];
    int tid = threadIdx.x;
    float4 v = bs[tid];                   // 1024 block sums = 256 thr x float4
    float s = (v.x + v.y) + (v.z + v.w);
#pragma unroll
    for (int off = 1; off <= 32; off <<= 1)
        s += __shfl_xor(s, off);
    int lane = tid & 63, wave = tid >> 6;
    if (lane == 0) ws[wave] = s;
    __syncthreads();
    if (tid == 0) out[0] = (ws[0] + ws[1] + ws[2] + ws[3]) * (1.0f / (float)NITEMS);
}

extern "C" void kernel_launch(void* const* d_in, const int* in_sizes, int n_in,
                              void* d_out, int out_size, void* d_ws, size_t ws_size,
                              hipStream_t stream) {
    const float* pred   = (const float*)d_in[0];
    const float* target = (const float*)d_in[1];
    float* out = (float*)d_out;

    float4* packP = (float4*)d_ws;                              // 1 MB
    float4* packT = packP + (size_t)BATCH * NPTS;               // 1 MB
    float*  blocksum = (float*)(packT + (size_t)BATCH * NPTS);  // 4 KB

    chamfer_prep<<<NITEMS / 256, 256, 0, stream>>>(pred, target, packP, packT);
    chamfer_main<<<MAIN_BLOCKS, THREADS, 0, stream>>>(packP, packT, blocksum);
    chamfer_finish<<<1, 256, 0, stream>>>((const float4*)blocksum, out);
}